// Round 10
// baseline (385.311 us; speedup 1.0000x reference)
//
#include <hip/hip_runtime.h>
#include <hip/hip_bf16.h>

#define BB 2
#define SS 2048
#define DD 256
#define HH 8
#define DKK 32
#define DVV 32
#define LL 3

typedef __hip_bfloat16 bf16;
typedef __attribute__((ext_vector_type(8))) short bfrag;
typedef __attribute__((ext_vector_type(4))) float f4;

__device__ __forceinline__ bfrag ld8(const bf16* p) {
  return *reinterpret_cast<const bfrag*>(p);
}

// ---------------- weight transpose + cast: wts[l][t][n][k] = W_t[l][k][n] ----------------
__global__ __launch_bounds__(256) void cast_weights_k(const float* __restrict__ wq,
                                                      const float* __restrict__ wk,
                                                      const float* __restrict__ wv,
                                                      const float* __restrict__ wfc,
                                                      bf16* __restrict__ wts) {
  int e = blockIdx.x * 256 + threadIdx.x;   // 786432 total
  int mat = e >> 16;                        // 0..11 = l*4 + t
  int t = mat & 3;
  int l = mat >> 2;
  int kk = (e >> 8) & 255;
  int n = e & 255;
  const float* src = (t == 0) ? wq : (t == 1) ? wk : (t == 2) ? wv : wfc;
  float v = src[((size_t)l * 256 + kk) * 256 + n];
  wts[(size_t)mat * 65536 + (size_t)n * 256 + kk] = __float2bfloat16(v);
}

// ---------------- x = seq + positional encoding, cast bf16 ----------------
__global__ __launch_bounds__(256) void pe_add_k(const float* __restrict__ seq,
                                                bf16* __restrict__ xbf) {
  int e = blockIdx.x * 256 + threadIdx.x;   // 1,048,576 total
  int d = e & 255;
  int m = e >> 8;
  int s = m & (SS - 1);
  int i2 = d >> 1;
  float div = __expf((float)(2 * i2) * (-9.210340371976184f / 256.0f));
  float ang = (float)s * div;
  float pe = (d & 1) ? __cosf(ang) : __sinf(ang);
  xbf[e] = __float2bfloat16(seq[e] + pe);
}

// ---------------- Q/K/V projection GEMM: [4096,256] @ [256,256]x3 ----------------
__global__ __launch_bounds__(256) void proj_k(const bf16* __restrict__ xbf,
                                              const bf16* __restrict__ wl,
                                              bf16* __restrict__ q,
                                              bf16* __restrict__ k,
                                              bf16* __restrict__ vt) {
  int lane = threadIdx.x & 63;
  int wv = threadIdx.x >> 6;
  int c = lane & 15, g = lane >> 4;
  int t = blockIdx.y >> 2;
  int n0 = (blockIdx.y & 3) * 64;
  int m0 = blockIdx.x * 64 + wv * 16;
  const bf16* wt = wl + (size_t)t * 65536;
  const bf16* arow = xbf + (size_t)(m0 + c) * 256 + g * 8;
  f4 acc[4];
#pragma unroll
  for (int i = 0; i < 4; ++i) acc[i] = (f4){0.f, 0.f, 0.f, 0.f};
#pragma unroll
  for (int kk = 0; kk < 8; ++kk) {
    bfrag af = ld8(arow + kk * 32);
#pragma unroll
    for (int ns = 0; ns < 4; ++ns) {
      bfrag bfr = ld8(wt + (size_t)(n0 + ns * 16 + c) * 256 + kk * 32 + g * 8);
      acc[ns] = __builtin_amdgcn_mfma_f32_16x16x32_bf16(af, bfr, acc[ns], 0, 0, 0);
    }
  }
#pragma unroll
  for (int ns = 0; ns < 4; ++ns) {
#pragma unroll
    for (int r = 0; r < 4; ++r) {
      int m = m0 + g * 4 + r;
      int n = n0 + ns * 16 + c;
      int b = m >> 11, s = m & (SS - 1);
      int h = n >> 5, d = n & 31;
      bf16 v = __float2bfloat16(acc[ns][r]);
      if (t == 0)      q[((size_t)(b * HH + h) * SS + s) * DKK + d] = v;
      else if (t == 1) k[((size_t)(b * HH + h) * SS + s) * DKK + d] = v;
      else             vt[((size_t)(b * HH + h) * DVV + d) * SS + s] = v;  // V transposed
    }
  }
}

// ---------------- FC GEMM: ctx[4096,256] @ Wfc[256,256] ----------------
__global__ __launch_bounds__(256) void fc_k(const bf16* __restrict__ ctxbf,
                                            const bf16* __restrict__ wt,
                                            bf16* __restrict__ xbf,
                                            float* __restrict__ fout, int wf) {
  int lane = threadIdx.x & 63;
  int wv = threadIdx.x >> 6;
  int c = lane & 15, g = lane >> 4;
  int n0 = blockIdx.y * 64;
  int m0 = blockIdx.x * 64 + wv * 16;
  const bf16* arow = ctxbf + (size_t)(m0 + c) * 256 + g * 8;
  f4 acc[4];
#pragma unroll
  for (int i = 0; i < 4; ++i) acc[i] = (f4){0.f, 0.f, 0.f, 0.f};
#pragma unroll
  for (int kk = 0; kk < 8; ++kk) {
    bfrag af = ld8(arow + kk * 32);
#pragma unroll
    for (int ns = 0; ns < 4; ++ns) {
      bfrag bfr = ld8(wt + (size_t)(n0 + ns * 16 + c) * 256 + kk * 32 + g * 8);
      acc[ns] = __builtin_amdgcn_mfma_f32_16x16x32_bf16(af, bfr, acc[ns], 0, 0, 0);
    }
  }
#pragma unroll
  for (int ns = 0; ns < 4; ++ns) {
#pragma unroll
    for (int r = 0; r < 4; ++r) {
      int m = m0 + g * 4 + r;
      int n = n0 + ns * 16 + c;
      float v = acc[ns][r];
      xbf[(size_t)m * 256 + n] = __float2bfloat16(v);
      if (wf) fout[(size_t)m * 256 + n] = v;
    }
  }
}

// ---------------- attention light (R3 form): ONE pass, sums + unnormalized PV ----------
__global__ __launch_bounds__(256) void attn_light_k(const bf16* __restrict__ q,
                                                    const bf16* __restrict__ k,
                                                    const bf16* __restrict__ vt,
                                                    float* __restrict__ inv_out,
                                                    bf16* __restrict__ ctxbf) {
  const float C2 = 0.2550350812540738f;  // log2(e)/sqrt(32)
  int lane = threadIdx.x & 63;
  int wv = threadIdx.x >> 6;
  int c = lane & 15, g = lane >> 4;
  int bh = blockIdx.y;
  int b = bh >> 3, h = bh & 7;
  int s0 = blockIdx.x * 64 + wv * 16;
  const bf16* qb = q + ((size_t)bh * SS + s0) * DKK;
  const bf16* kb = k + (size_t)bh * SS * DKK;
  const bf16* vb = vt + (size_t)bh * DVV * SS;
  bfrag qf = ld8(qb + c * DKK + g * 8);
  const f4 z = {0.f, 0.f, 0.f, 0.f};

  __shared__ __align__(16) bf16 pbf[4][16][40];  // 32 cols + 8 pad
  float sums[4] = {0.f, 0.f, 0.f, 0.f};
  f4 acc0 = z, acc1 = z;
  for (int kc2 = 0; kc2 < SS / 32; ++kc2) {
#pragma unroll
    for (int t = 0; t < 2; ++t) {
      bfrag kf = ld8(kb + (size_t)(kc2 * 32 + t * 16 + c) * DKK + g * 8);
      f4 sc = __builtin_amdgcn_mfma_f32_16x16x32_bf16(qf, kf, z, 0, 0, 0);
#pragma unroll
      for (int r = 0; r < 4; ++r) {
        float e = __builtin_amdgcn_exp2f(sc[r] * C2);
        sums[r] += e;
        pbf[wv][g * 4 + r][t * 16 + c] = __float2bfloat16(e);
      }
    }
    bfrag pa = ld8(&pbf[wv][c][g * 8]);
    bfrag vf0 = ld8(vb + (size_t)c * SS + kc2 * 32 + g * 8);
    acc0 = __builtin_amdgcn_mfma_f32_16x16x32_bf16(pa, vf0, acc0, 0, 0, 0);
    bfrag vf1 = ld8(vb + (size_t)(16 + c) * SS + kc2 * 32 + g * 8);
    acc1 = __builtin_amdgcn_mfma_f32_16x16x32_bf16(pa, vf1, acc1, 0, 0, 0);
  }
#pragma unroll
  for (int mm = 1; mm < 16; mm <<= 1) {
#pragma unroll
    for (int r = 0; r < 4; ++r) sums[r] += __shfl_xor(sums[r], mm, 64);
  }
#pragma unroll
  for (int r = 0; r < 4; ++r) {
    float iv = 1.0f / sums[r];
    if (c == 0) inv_out[(size_t)bh * SS + s0 + g * 4 + r] = iv;
    int srow = s0 + g * 4 + r;
    size_t base = ((size_t)b * SS + srow) * 256 + h * 32;
    ctxbf[base + c] = __float2bfloat16(acc0[r] * iv);
    ctxbf[base + 16 + c] = __float2bfloat16(acc1[r] * iv);
  }
}

// ---------------- attention store v4: 1-wave blocks, 1KB-contiguous drain ----------
// Counter-driven redesign (R8: VALU 19%, Mfma 3%, occ 33%, 4.9 TB/s vs fill's
// 6.6 at 256B chunks). Each 64-thr block (1 wave) owns 16 q-rows; accumulates
// 16x256 fp32 in a 16KB XOR-swizzled LDS tile; drains 16 stores of 1KB fully
// contiguous (64 lanes x dwordx4) — per-instruction identical to the 6.6 TB/s
// fill kernel. 10 blocks/CU resident (LDS cap), independent waves, no nt.
__global__ __launch_bounds__(64) void attn_store_k(const bf16* __restrict__ qs,
                                                   const bf16* __restrict__ ks,
                                                   const float* __restrict__ inv,
                                                   float* __restrict__ aout) {
  const float C2 = 0.2550350812540738f;
  int l64 = threadIdx.x;            // 0..63
  int c = l64 & 15, g = l64 >> 4;
  int lbh = blockIdx.z * BB * HH + blockIdx.y;   // layer*16 + bh
  int s0 = blockIdx.x * 16;
  const bf16* qb = qs + ((size_t)lbh * SS + s0) * DKK;
  const bf16* kb = ks + (size_t)lbh * SS * DKK;
  bfrag qf = ld8(qb + c * DKK + g * 8);
  f4 invr = *reinterpret_cast<const f4*>(inv + (size_t)lbh * SS + s0 + g * 4);
  const f4 z = {0.f, 0.f, 0.f, 0.f};

  __shared__ __align__(16) float pw[16 * 256];   // 16 KB, rows of 256 cols
  float* arow = aout + ((size_t)lbh * SS + s0) * SS;

  // group-granular channel-phase stagger (multiple of 4 chunks = 256 cols)
  int ph = ((blockIdx.x + blockIdx.y * 5 + blockIdx.z * 11) & 7) * 4;

  bfrag kfn[4];
#pragma unroll
  for (int t = 0; t < 4; ++t)
    kfn[t] = ld8(kb + (size_t)(ph * 64 + t * 16 + c) * DKK + g * 8);

  for (int jj = 0; jj < 32; ++jj) {
    int kc = (jj + ph) & 31;        // staggered chunk index (64 cols)
    int kcn = (jj + 1 + ph) & 31;   // wraps on last iter: harmless re-read
    bfrag kfc[4];
#pragma unroll
    for (int t = 0; t < 4; ++t) kfc[t] = kfn[t];
#pragma unroll
    for (int t = 0; t < 4; ++t)
      kfn[t] = ld8(kb + (size_t)(kcn * 64 + t * 16 + c) * DKK + g * 8);
    int cp = jj & 3;                // chunk position within 256-col group
#pragma unroll
    for (int t = 0; t < 4; ++t) {
      f4 sc = __builtin_amdgcn_mfma_f32_16x16x32_bf16(qf, kfc[t], z, 0, 0, 0);
#pragma unroll
      for (int r = 0; r < 4; ++r) {
        float p = __builtin_amdgcn_exp2f(sc[r] * C2) * invr[r];
        int row = g * 4 + r;
        int F = cp * 16 + t * 4 + (c >> 2);       // col-quad 0..63
        pw[row * 256 + ((F ^ row) << 2) + (c & 3)] = p;  // swizzled: 2 lanes/bank
      }
    }
    if (cp == 3) {
      int grp = kc >> 2;            // 256-col group index (already staggered)
      float* gbase = arow + (grp << 8);
#pragma unroll
      for (int rr = 0; rr < 16; ++rr) {
        f4 v = *reinterpret_cast<f4*>(&pw[rr * 256 + ((l64 ^ rr) << 2)]);
        *reinterpret_cast<f4*>(&gbase[(size_t)rr * SS + (l64 << 2)]) = v;
      }
    }
  }
}

extern "C" void kernel_launch(void* const* d_in, const int* in_sizes, int n_in,
                              void* d_out, int out_size, void* d_ws, size_t ws_size,
                              hipStream_t stream) {
  (void)in_sizes; (void)n_in; (void)out_size; (void)ws_size;
  const float* seq = (const float*)d_in[0];
  const float* Wq  = (const float*)d_in[1];
  const float* Wk  = (const float*)d_in[2];
  const float* Wv  = (const float*)d_in[3];
  const float* Wfc = (const float*)d_in[4];
  float* out = (float*)d_out;
  float* attns = out + (size_t)BB * SS * DD;

  const size_t MB2 = 2097152;
  char* ws = (char*)d_ws;
  bf16* wts  = (bf16*)(ws);                       // 1.5 MB
  bf16* xbf  = (bf16*)(ws + 1572864);             // 2 MB
  bf16* vtb  = (bf16*)(ws + 1572864 + MB2);       // 2 MB
  bf16* ctxb = (bf16*)(ws + 1572864 + 2 * MB2);   // 2 MB
  bf16* qs   = (bf16*)(ws + 1572864 + 3 * MB2);   // 3 x 2 MB
  bf16* ks   = (bf16*)(ws + 1572864 + 6 * MB2);   // 3 x 2 MB
  float* invb = (float*)(ws + 1572864 + 9 * MB2); // 384 KB

  cast_weights_k<<<3072, 256, 0, stream>>>(Wq, Wk, Wv, Wfc, wts);
  pe_add_k<<<4096, 256, 0, stream>>>(seq, xbf);

  for (int l = 0; l < LL; ++l) {
    bf16* ql = qs + (size_t)l * BB * HH * SS * DKK;
    bf16* kl = ks + (size_t)l * BB * HH * SS * DKK;
    float* invl = invb + (size_t)l * BB * HH * SS;
    proj_k<<<dim3(64, 12), 256, 0, stream>>>(xbf, wts + (size_t)l * 4 * 65536, ql, kl, vtb);
    attn_light_k<<<dim3(SS / 64, BB * HH), 256, 0, stream>>>(ql, kl, vtb, invl, ctxb);
    fc_k<<<dim3(64, 4), 256, 0, stream>>>(ctxb, wts + ((size_t)l * 4 + 3) * 65536,
                                          xbf, out, (l == LL - 1) ? 1 : 0);
  }
  attn_store_k<<<dim3(SS / 16, BB * HH, LL), 64, 0, stream>>>(qs, ks, invb, attns);
}

// Round 11
// 343.969 us; speedup vs baseline: 1.1202x; 1.1202x over previous
//
#include <hip/hip_runtime.h>
#include <hip/hip_bf16.h>

#define BB 2
#define SS 2048
#define DD 256
#define HH 8
#define DKK 32
#define DVV 32
#define LL 3

typedef __hip_bfloat16 bf16;
typedef __attribute__((ext_vector_type(8))) short bfrag;
typedef __attribute__((ext_vector_type(4))) float f4;

__device__ __forceinline__ bfrag ld8(const bf16* p) {
  return *reinterpret_cast<const bfrag*>(p);
}

// ---------------- weight transpose + cast: wts[l][t][n][k] = W_t[l][k][n] ----------------
__global__ __launch_bounds__(256) void cast_weights_k(const float* __restrict__ wq,
                                                      const float* __restrict__ wk,
                                                      const float* __restrict__ wv,
                                                      const float* __restrict__ wfc,
                                                      bf16* __restrict__ wts) {
  int e = blockIdx.x * 256 + threadIdx.x;   // 786432 total
  int mat = e >> 16;                        // 0..11 = l*4 + t
  int t = mat & 3;
  int l = mat >> 2;
  int kk = (e >> 8) & 255;
  int n = e & 255;
  const float* src = (t == 0) ? wq : (t == 1) ? wk : (t == 2) ? wv : wfc;
  float v = src[((size_t)l * 256 + kk) * 256 + n];
  wts[(size_t)mat * 65536 + (size_t)n * 256 + kk] = __float2bfloat16(v);
}

// ---------------- x = seq + positional encoding, cast bf16 ----------------
__global__ __launch_bounds__(256) void pe_add_k(const float* __restrict__ seq,
                                                bf16* __restrict__ xbf) {
  int e = blockIdx.x * 256 + threadIdx.x;   // 1,048,576 total
  int d = e & 255;
  int m = e >> 8;
  int s = m & (SS - 1);
  int i2 = d >> 1;
  float div = __expf((float)(2 * i2) * (-9.210340371976184f / 256.0f));
  float ang = (float)s * div;
  float pe = (d & 1) ? __cosf(ang) : __sinf(ang);
  xbf[e] = __float2bfloat16(seq[e] + pe);
}

// ---------------- Q/K/V projection GEMM: [4096,256] @ [256,256]x3 ----------------
__global__ __launch_bounds__(256) void proj_k(const bf16* __restrict__ xbf,
                                              const bf16* __restrict__ wl,
                                              bf16* __restrict__ q,
                                              bf16* __restrict__ k,
                                              bf16* __restrict__ vt) {
  int lane = threadIdx.x & 63;
  int wv = threadIdx.x >> 6;
  int c = lane & 15, g = lane >> 4;
  int t = blockIdx.y >> 2;
  int n0 = (blockIdx.y & 3) * 64;
  int m0 = blockIdx.x * 64 + wv * 16;
  const bf16* wt = wl + (size_t)t * 65536;
  const bf16* arow = xbf + (size_t)(m0 + c) * 256 + g * 8;
  f4 acc[4];
#pragma unroll
  for (int i = 0; i < 4; ++i) acc[i] = (f4){0.f, 0.f, 0.f, 0.f};
#pragma unroll
  for (int kk = 0; kk < 8; ++kk) {
    bfrag af = ld8(arow + kk * 32);
#pragma unroll
    for (int ns = 0; ns < 4; ++ns) {
      bfrag bfr = ld8(wt + (size_t)(n0 + ns * 16 + c) * 256 + kk * 32 + g * 8);
      acc[ns] = __builtin_amdgcn_mfma_f32_16x16x32_bf16(af, bfr, acc[ns], 0, 0, 0);
    }
  }
#pragma unroll
  for (int ns = 0; ns < 4; ++ns) {
#pragma unroll
    for (int r = 0; r < 4; ++r) {
      int m = m0 + g * 4 + r;
      int n = n0 + ns * 16 + c;
      int b = m >> 11, s = m & (SS - 1);
      int h = n >> 5, d = n & 31;
      bf16 v = __float2bfloat16(acc[ns][r]);
      if (t == 0)      q[((size_t)(b * HH + h) * SS + s) * DKK + d] = v;
      else if (t == 1) k[((size_t)(b * HH + h) * SS + s) * DKK + d] = v;
      else             vt[((size_t)(b * HH + h) * DVV + d) * SS + s] = v;  // V transposed
    }
  }
}

// ---------------- FC GEMM: ctx[4096,256] @ Wfc[256,256] ----------------
__global__ __launch_bounds__(256) void fc_k(const bf16* __restrict__ ctxbf,
                                            const bf16* __restrict__ wt,
                                            bf16* __restrict__ xbf,
                                            float* __restrict__ fout, int wf) {
  int lane = threadIdx.x & 63;
  int wv = threadIdx.x >> 6;
  int c = lane & 15, g = lane >> 4;
  int n0 = blockIdx.y * 64;
  int m0 = blockIdx.x * 64 + wv * 16;
  const bf16* arow = ctxbf + (size_t)(m0 + c) * 256 + g * 8;
  f4 acc[4];
#pragma unroll
  for (int i = 0; i < 4; ++i) acc[i] = (f4){0.f, 0.f, 0.f, 0.f};
#pragma unroll
  for (int kk = 0; kk < 8; ++kk) {
    bfrag af = ld8(arow + kk * 32);
#pragma unroll
    for (int ns = 0; ns < 4; ++ns) {
      bfrag bfr = ld8(wt + (size_t)(n0 + ns * 16 + c) * 256 + kk * 32 + g * 8);
      acc[ns] = __builtin_amdgcn_mfma_f32_16x16x32_bf16(af, bfr, acc[ns], 0, 0, 0);
    }
  }
#pragma unroll
  for (int ns = 0; ns < 4; ++ns) {
#pragma unroll
    for (int r = 0; r < 4; ++r) {
      int m = m0 + g * 4 + r;
      int n = n0 + ns * 16 + c;
      float v = acc[ns][r];
      xbf[(size_t)m * 256 + n] = __float2bfloat16(v);
      if (wf) fout[(size_t)m * 256 + n] = v;
    }
  }
}

// ---------------- FUSED attention: sums pass + (recompute -> store + PV) pass -------
// Replaces attn_light + attn_store. grid (SS/64, B*H) per layer, 256 thr.
// Each wave owns 16 q-rows; all LDS strictly per-wave -> no barriers.
// Pass 1: in-register QK^T -> exp2 -> row sums (no LDS, no stores).
// Pass 2: recompute QK^T, p = exp2(s)*inv; p goes (a) into the XOR-swizzled
// fp32 LDS tile, drained as 4x256B-contiguous dwordx4 stores per 64-col chunk
// (measured-best store pattern, R8), and (b) as bf16 into the PV tile feeding
// PV MFMAs that hide under the store drain. ctx comes out normalized.
__global__ __launch_bounds__(256) void attn_full_k(const bf16* __restrict__ q,
                                                   const bf16* __restrict__ k,
                                                   const bf16* __restrict__ vt,
                                                   float* __restrict__ aout,
                                                   bf16* __restrict__ ctxbf) {
  const float C2 = 0.2550350812540738f;  // log2(e)/sqrt(32)
  int lane = threadIdx.x & 63;
  int wv = threadIdx.x >> 6;
  int c = lane & 15, g = lane >> 4;
  int bh = blockIdx.y;
  int b = bh >> 3, h = bh & 7;
  int s0 = blockIdx.x * 64 + wv * 16;
  const bf16* qb = q + ((size_t)bh * SS + s0) * DKK;
  const bf16* kb = k + (size_t)bh * SS * DKK;
  const bf16* vb = vt + (size_t)bh * DVV * SS;
  bfrag qf = ld8(qb + c * DKK + g * 8);
  const f4 z = {0.f, 0.f, 0.f, 0.f};

  // ---- pass 1: row sums of exp(s), fully in-register ----
  float sums[4] = {0.f, 0.f, 0.f, 0.f};
#pragma unroll 4
  for (int kc = 0; kc < SS / 16; ++kc) {
    bfrag kf = ld8(kb + (size_t)(kc * 16 + c) * DKK + g * 8);
    f4 sc = __builtin_amdgcn_mfma_f32_16x16x32_bf16(qf, kf, z, 0, 0, 0);
#pragma unroll
    for (int r = 0; r < 4; ++r) sums[r] += __builtin_amdgcn_exp2f(sc[r] * C2);
  }
#pragma unroll
  for (int mm = 1; mm < 16; mm <<= 1) {
#pragma unroll
    for (int r = 0; r < 4; ++r) sums[r] += __shfl_xor(sums[r], mm, 64);
  }
  float invr[4];
#pragma unroll
  for (int r = 0; r < 4; ++r) invr[r] = 1.0f / sums[r];

  // ---- pass 2: recompute, store p, accumulate PV ----
  __shared__ __align__(16) float pws[4][16 * 64];   // fp32 store-bounce, swizzled
  __shared__ __align__(16) bf16 pbf[4][16][40];     // bf16 PV tile (32 + 8 pad)
  float* pw = pws[wv];
  float* arow = aout + ((size_t)bh * SS + s0) * SS;
  f4 acc0 = z, acc1 = z;

  for (int j = 0; j < SS / 64; ++j) {
#pragma unroll
    for (int half = 0; half < 2; ++half) {
#pragma unroll
      for (int t2 = 0; t2 < 2; ++t2) {
        int t = half * 2 + t2;
        bfrag kf = ld8(kb + (size_t)(j * 64 + t * 16 + c) * DKK + g * 8);
        f4 sc = __builtin_amdgcn_mfma_f32_16x16x32_bf16(qf, kf, z, 0, 0, 0);
#pragma unroll
        for (int r = 0; r < 4; ++r) {
          float p = __builtin_amdgcn_exp2f(sc[r] * C2) * invr[r];
          int row = g * 4 + r;
          int col = t * 16 + c;
          pw[row * 64 + (((col >> 2) ^ row) << 2) + (col & 3)] = p;
          pbf[wv][row][t2 * 16 + c] = __float2bfloat16(p);
        }
      }
      bfrag pa = ld8(&pbf[wv][c][g * 8]);
      bfrag vf0 = ld8(vb + (size_t)c * SS + j * 64 + half * 32 + g * 8);
      acc0 = __builtin_amdgcn_mfma_f32_16x16x32_bf16(pa, vf0, acc0, 0, 0, 0);
      bfrag vf1 = ld8(vb + (size_t)(16 + c) * SS + j * 64 + half * 32 + g * 8);
      acc1 = __builtin_amdgcn_mfma_f32_16x16x32_bf16(pa, vf1, acc1, 0, 0, 0);
    }
#pragma unroll
    for (int qq = 0; qq < 4; ++qq) {
      int row = qq * 4 + g;
      f4 v = *reinterpret_cast<f4*>(&pw[row * 64 + ((c ^ row) << 2)]);
      *reinterpret_cast<f4*>(&arow[(size_t)row * SS + j * 64 + (c << 2)]) = v;
    }
  }

  // ---- epilogue: ctx already normalized ----
#pragma unroll
  for (int r = 0; r < 4; ++r) {
    int srow = s0 + g * 4 + r;
    size_t base = ((size_t)b * SS + srow) * 256 + h * 32;
    ctxbf[base + c] = __float2bfloat16(acc0[r]);
    ctxbf[base + 16 + c] = __float2bfloat16(acc1[r]);
  }
}

extern "C" void kernel_launch(void* const* d_in, const int* in_sizes, int n_in,
                              void* d_out, int out_size, void* d_ws, size_t ws_size,
                              hipStream_t stream) {
  (void)in_sizes; (void)n_in; (void)out_size; (void)ws_size;
  const float* seq = (const float*)d_in[0];
  const float* Wq  = (const float*)d_in[1];
  const float* Wk  = (const float*)d_in[2];
  const float* Wv  = (const float*)d_in[3];
  const float* Wfc = (const float*)d_in[4];
  float* out = (float*)d_out;
  float* attns = out + (size_t)BB * SS * DD;

  const size_t MB2 = 2097152;
  char* ws = (char*)d_ws;
  bf16* wts  = (bf16*)(ws);                       // 1.5 MB
  bf16* xbf  = (bf16*)(ws + 1572864);             // 2 MB
  bf16* vtb  = (bf16*)(ws + 1572864 + MB2);       // 2 MB
  bf16* ctxb = (bf16*)(ws + 1572864 + 2 * MB2);   // 2 MB
  bf16* qb   = (bf16*)(ws + 1572864 + 3 * MB2);   // 2 MB
  bf16* kb   = (bf16*)(ws + 1572864 + 4 * MB2);   // 2 MB

  cast_weights_k<<<3072, 256, 0, stream>>>(Wq, Wk, Wv, Wfc, wts);
  pe_add_k<<<4096, 256, 0, stream>>>(seq, xbf);

  for (int l = 0; l < LL; ++l) {
    proj_k<<<dim3(64, 12), 256, 0, stream>>>(xbf, wts + (size_t)l * 4 * 65536, qb, kb, vtb);
    attn_full_k<<<dim3(SS / 64, BB * HH), 256, 0, stream>>>(
        qb, kb, vtb, attns + (size_t)l * BB * HH * SS * SS, ctxb);
    fc_k<<<dim3(64, 4), 256, 0, stream>>>(ctxb, wts + ((size_t)l * 4 + 3) * 65536,
                                          xbf, out, (l == LL - 1) ? 1 : 0);
  }
}